// Round 9
// baseline (222.349 us; speedup 1.0000x reference)
//
#include <hip/hip_runtime.h>
#include <hip/hip_bf16.h>
#include <stdint.h>

// ScaledDotProductAttention S=4096 D=1024 fp32.
// R17: split the staging across two HW paths. Measured law (R14/R15/R16/m97):
// global_load_lds streams ~8 B/cy per concurrently-streaming BLOCK and resident
// blocks can't be forced above ~1.2-2. So: move A (32 of 48 KB/K-step) OFF the
// DMA path. 8M x 1N wave layout (wave owns a 32x128 output strip) makes each
// wave's A fragments exclusive -> A loads straight global->VGPR (ordinary
// dwordx4, 16 rows x 64B contiguous per wave-instr, each byte read once per
// block); B (16 KB/step, shared by all 8 waves) keeps the proven DMA+swizzle,
// now double-buffered. Per-block DMA floor = 16KB/step / 8 B/cy = 2048 cy ->
// ~13.7us/dispatch; A-loads (~16 B/cy from L2) + MFMA (13.8us) hide under it.
// Tile/grids unchanged (BM=256 BN=128 BK=64, 384/512/512 blocks, XCD decode).
// Epilogues re-indexed for strips: j-inner stores now 256B runs (R13 WC fix);
// V^T 2-pass LDS transpose keeps R11-proven 264-stride + full-line drain.

typedef __bf16 bf16_t;
typedef __bf16 bf16x4 __attribute__((ext_vector_type(4)));
typedef __bf16 bf16x8 __attribute__((ext_vector_type(8)));
typedef float f32x4 __attribute__((ext_vector_type(4)));

#define AS1 __attribute__((address_space(1)))
#define AS3 __attribute__((address_space(3)))

__device__ __forceinline__ void async_ld16(const void* g, void* l) {
  // global -> LDS DMA, 16B/lane; LDS dest is wave-uniform base + lane*16 by HW rule.
  __builtin_amdgcn_global_load_lds((AS1 void*)g, (AS3 void*)l, 16, 0, 0);
}

// BM=256, BN=128, BK=64, 8 waves (8M x 1N), per-wave 32x128 strip = acc[2][8].
// LDS: 2 x Bs(128x64) double-buffer (32KB) | V^T scratch (33792B max) = 33792B.
// MODE 0: QKV epilogue (bias; Q scaled 1/32; V transposed via LDS).
// MODE 1: S epilogue: store exp(acc) bf16 ldc=4096, atomicAdd fp32 row sums.
// MODE 2: O epilogue: zz<3 -> bf16 partial; zz==3 -> fp32 to fout (1/rowsum).
template <int MODE>
__global__ __launch_bounds__(512, 4) void gemm3(
    const bf16_t* __restrict__ A, const bf16_t* __restrict__ B, const int ld,
    const int Klen, bf16_t* __restrict__ o0, bf16_t* __restrict__ o1,
    bf16_t* __restrict__ o2, const float* __restrict__ b0,
    const float* __restrict__ b1, const float* __restrict__ b2,
    float* __restrict__ fout, float* __restrict__ rowsum) {
  __shared__ bf16_t smem[16896];  // 33792 B
  bf16_t* bufB0 = smem;           // 8192 elems
  bf16_t* bufB1 = smem + 8192;

  const int t = threadIdx.x;
  const int lane = t & 63;
  const int w = t >> 6;    // wave 0..7 = M strip (32 rows)
  const int q = lane >> 4;
  const int l16 = lane & 15;
  const int xf = l16 & 7;

  // Grid decode: XCD-aware (bid&7 = XCD), bijective per mode (R16-proven).
  int m0, n0, k0 = 0, zz = 0;
  const int bid = blockIdx.x;
  if constexpr (MODE == 0) {
    // 384 blocks = 16m x 24n; per XCD: 4m x 12n region.
    const int x = bid & 7, sl = bid >> 3;  // sl 0..47
    m0 = ((x >> 1) * 4 + (sl & 3)) * 256;
    n0 = ((x & 1) * 12 + (sl >> 2)) * 128;
  } else if constexpr (MODE == 1) {
    // 512 blocks = 16m x 32n; per XCD: 8m x 8n region.
    const int x = bid & 7, sl = bid >> 3;  // sl 0..63
    m0 = ((x >> 2) * 8 + (sl >> 3)) * 256;
    n0 = ((x & 3) * 8 + (sl & 7)) * 128;
  } else {
    // 512 blocks: split-K z = x>>1; per XCD: 8m x 8n of one split (N=1024).
    const int x = bid & 7, sl = bid >> 3;  // sl 0..63
    zz = x >> 1;
    m0 = ((x & 1) * 8 + (sl >> 3)) * 256;
    n0 = (sl & 7) * 128;
    k0 = zz * Klen;
  }

  // B staging swizzle (R5-proven): GLOBAL chunk = slot ^ (srow&7); LDS linear.
  // 64 rows x 64 k per round (1 load/thread), 2 rounds = 128 rows.
  const int srow = t >> 3;                      // 0..63
  const int c8s = ((t & 7) ^ (srow & 7)) * 8;
  const bf16_t* Bb = B + (size_t)(n0 + srow) * ld + k0 + c8s;
  const int tl8 = t * 8;

  // A direct: per-lane row base (wave-exclusive rows -> each byte read once).
  const bf16_t* Ap = A + (size_t)(m0 + w * 32 + l16) * ld + k0 + q * 8;
  const size_t a16 = (size_t)16 * ld;  // im stride (elems)

  f32x4 acc[2][8];
  const f32x4 zero4 = {0.f, 0.f, 0.f, 0.f};
#pragma unroll
  for (int i = 0; i < 2; ++i)
#pragma unroll
    for (int j = 0; j < 8; ++j) acc[i][j] = zero4;

  const int NT = Klen >> 6;

  auto STAGE_B = [&](int T, bf16_t* buf) {
    const int kk = T << 6;
    async_ld16(Bb + kk, buf + tl8);
    async_ld16(Bb + (size_t)64 * ld + kk, buf + 4096 + tl8);
  };

  STAGE_B(0, bufB0);
  __syncthreads();  // vmcnt(0)+barrier: B(0) resident

  for (int T = 0; T < NT; ++T) {
    bf16_t* cur = (T & 1) ? bufB1 : bufB0;
    bf16_t* nxt = (T & 1) ? bufB0 : bufB1;
    if (T + 1 < NT) STAGE_B(T + 1, nxt);  // DMA in flight across compute
    const int kk = T << 6;

#pragma unroll
    for (int s = 0; s < 2; ++s) {
      bf16x8 fa[2], fb[8];
#pragma unroll
      for (int im = 0; im < 2; ++im)
        fa[im] = *(const bf16x8*)(Ap + (size_t)im * a16 + kk + s * 32);
      const int cs = ((s * 4 + q) ^ xf) * 8;
#pragma unroll
      for (int j = 0; j < 8; ++j)
        fb[j] = *(const bf16x8*)(cur + (j * 16 + l16) * 64 + cs);
#pragma unroll
      for (int im = 0; im < 2; ++im)
#pragma unroll
        for (int j = 0; j < 8; ++j)
          acc[im][j] = __builtin_amdgcn_mfma_f32_16x16x32_bf16(
              fa[im], fb[j], acc[im][j], 0, 0, 0);
    }
    __syncthreads();  // drains B(T+1) DMA + fa loads + fb reads
  }

  // C/D layout: col = lane&15, row = quad*4 + reg (m89/m91-verified).
  const int mBase = m0 + w * 32 + q * 4;  // + im*16 + r

  if constexpr (MODE == 0) {
    const int sel = n0 >> 10;  // 0=Q 1=K 2=V  (128-tiles never straddle)
    const int nl0 = (n0 & 1023) + l16;
    if (sel < 2) {
      const float* bias = (sel == 0) ? b0 : b1;
      const float sc = (sel == 0) ? 0.03125f : 1.0f;  // 1/sqrt(1024) in Q
      bf16_t* dst = (sel == 0) ? o0 : o1;
      float bb[8];
#pragma unroll
      for (int j = 0; j < 8; ++j) bb[j] = bias[nl0 + j * 16];
      // j INNERMOST: 8 consecutive stores complete each 256B run (R13 fix).
#pragma unroll
      for (int im = 0; im < 2; ++im) {
        const int mr = mBase + im * 16;
#pragma unroll
        for (int r = 0; r < 4; ++r)
#pragma unroll
          for (int j = 0; j < 8; ++j)
            dst[(size_t)(mr + r) * 1024 + nl0 + j * 16] =
                (bf16_t)((acc[im][j][r] + bb[j]) * sc);
      }
    } else {
      // V^T via LDS transpose: two passes of 64 d-rows x 256 m (j-halves).
      // Stride 264 elems (R11-proven write pattern); drain 16B/lane, 512B
      // contiguous per Vt row -> full-line stores.
      bf16_t* vs = smem;  // 64*264*2 = 33792 B (K-loop buffers dead)
      const int dg0 = n0 & 1023;
#pragma unroll
      for (int h = 0; h < 2; ++h) {
#pragma unroll
        for (int jj = 0; jj < 4; ++jj) {
          const int dl = jj * 16 + l16;  // 0..63 within this half
          const float bb = b2[dg0 + h * 64 + dl];
#pragma unroll
          for (int im = 0; im < 2; ++im) {
            bf16x4 v;
#pragma unroll
            for (int r = 0; r < 4; ++r)
              v[r] = (bf16_t)(acc[im][h * 4 + jj][r] + bb);
            *(bf16x4*)(vs + dl * 264 + w * 32 + im * 16 + q * 4) = v;
          }
        }
        __syncthreads();
#pragma unroll
        for (int rr = 0; rr < 4; ++rr) {
          const int task = rr * 512 + t;  // 2048 tasks = 64 rows x 32 chunks
          const int row = task >> 5, ck = task & 31;
          *(bf16x8*)(o2 + (size_t)(dg0 + h * 64 + row) * 4096 + m0 + ck * 8) =
              *(const bf16x8*)(vs + row * 264 + ck * 8);
        }
        __syncthreads();
      }
    }
  } else if constexpr (MODE == 1) {
    float ps[2][4];
#pragma unroll
    for (int im = 0; im < 2; ++im)
#pragma unroll
      for (int r = 0; r < 4; ++r) ps[im][r] = 0.f;
    const int nb = n0 + l16;
    // j INNERMOST: 256B runs back-to-back (R13 write-combine fix).
#pragma unroll
    for (int im = 0; im < 2; ++im) {
      const int mr = mBase + im * 16;
#pragma unroll
      for (int r = 0; r < 4; ++r)
#pragma unroll
        for (int j = 0; j < 8; ++j) {
          const float e = __expf(acc[im][j][r]);
          ps[im][r] += e;
          o0[(size_t)(mr + r) * 4096 + nb + j * 16] = (bf16_t)e;
        }
    }
#pragma unroll
    for (int im = 0; im < 2; ++im)
#pragma unroll
      for (int r = 0; r < 4; ++r) {
        float v = ps[im][r];
        v += __shfl_xor(v, 1);
        v += __shfl_xor(v, 2);
        v += __shfl_xor(v, 4);
        v += __shfl_xor(v, 8);
        ps[im][r] = v;
      }
    if (l16 == 0) {
#pragma unroll
      for (int im = 0; im < 2; ++im)
#pragma unroll
        for (int r = 0; r < 4; ++r)
          atomicAdd(rowsum + mBase + im * 16 + r, ps[im][r]);
    }
  } else {
    float inv[2][4];
#pragma unroll
    for (int im = 0; im < 2; ++im)
#pragma unroll
      for (int r = 0; r < 4; ++r)
        inv[im][r] = 1.0f / rowsum[mBase + im * 16 + r];
    const int nb = n0 + l16;
    if (zz < 3) {  // bf16 partial (normalized); partials over splits sum to O
      bf16_t* pp = (zz == 0) ? o0 : ((zz == 1) ? o1 : o2);
#pragma unroll
      for (int im = 0; im < 2; ++im) {
        const int mr = mBase + im * 16;
#pragma unroll
        for (int r = 0; r < 4; ++r) {
          const float iv = inv[im][r];
#pragma unroll
          for (int j = 0; j < 8; ++j)
            pp[(size_t)(mr + r) * 1024 + nb + j * 16] =
                (bf16_t)(acc[im][j][r] * iv);
        }
      }
    } else {  // zz==3: fp32 partial straight into d_out; reduce adds the rest
#pragma unroll
      for (int im = 0; im < 2; ++im) {
        const int mr = mBase + im * 16;
#pragma unroll
        for (int r = 0; r < 4; ++r) {
          const float iv = inv[im][r];
#pragma unroll
          for (int j = 0; j < 8; ++j)
            fout[(size_t)(mr + r) * 1024 + nb + j * 16] = acc[im][j][r] * iv;
        }
      }
    }
  }
}

// Converts X|Wq|Wk|Wv to bf16; last 16 blocks zero rowsum (4096 f32).
__global__ __launch_bounds__(256) void cvt_all(
    const float* __restrict__ X, const float* __restrict__ Wq,
    const float* __restrict__ Wk, const float* __restrict__ Wv,
    bf16_t* __restrict__ Xb, bf16_t* __restrict__ Wb,
    float* __restrict__ rowsum) {
  int i = blockIdx.x * 256 + threadIdx.x;
  if (i >= 1835008) {
    rowsum[i - 1835008] = 0.f;
    return;
  }
  const float* src;
  bf16_t* dst;
  int off;
  if (i < 1048576) {
    src = X; dst = Xb; off = i;
  } else {
    const int w = i - 1048576;
    const int sel = w >> 18;
    off = w & 0x3FFFF;
    src = (sel == 0) ? Wq : ((sel == 1) ? Wk : Wv);
    dst = Wb + (size_t)sel * (1024 * 1024);
  }
  const float4 v = ((const float4*)src)[off];
  bf16x4 o;
  o[0] = (bf16_t)v.x; o[1] = (bf16_t)v.y; o[2] = (bf16_t)v.z; o[3] = (bf16_t)v.w;
  ((bf16x4*)dst)[off] = o;
}

// out[i] += f32(p0[i]) + f32(p1[i]) + f32(p2[i]);  8 elems/thread.
__global__ __launch_bounds__(256) void reduce_out(
    const bf16_t* __restrict__ p0, const bf16_t* __restrict__ p1,
    const bf16_t* __restrict__ p2, float* __restrict__ out) {
  const int i = blockIdx.x * 256 + threadIdx.x;
  const bf16x8 a = ((const bf16x8*)p0)[i];
  const bf16x8 b = ((const bf16x8*)p1)[i];
  const bf16x8 c = ((const bf16x8*)p2)[i];
  float4 lo = ((const float4*)out)[2 * i];
  float4 hi = ((const float4*)out)[2 * i + 1];
  lo.x += (float)a[0] + (float)b[0] + (float)c[0];
  lo.y += (float)a[1] + (float)b[1] + (float)c[1];
  lo.z += (float)a[2] + (float)b[2] + (float)c[2];
  lo.w += (float)a[3] + (float)b[3] + (float)c[3];
  hi.x += (float)a[4] + (float)b[4] + (float)c[4];
  hi.y += (float)a[5] + (float)b[5] + (float)c[5];
  hi.z += (float)a[6] + (float)b[6] + (float)c[6];
  hi.w += (float)a[7] + (float)b[7] + (float)c[7];
  ((float4*)out)[2 * i] = lo;
  ((float4*)out)[2 * i + 1] = hi;
}

extern "C" void kernel_launch(void* const* d_in, const int* in_sizes, int n_in,
                              void* d_out, int out_size, void* d_ws,
                              size_t ws_size, hipStream_t stream) {
  const int S = 4096, D = 1024;
  const float* X  = (const float*)d_in[0];
  const float* Wq = (const float*)d_in[1];
  const float* bq = (const float*)d_in[2];
  const float* Wk = (const float*)d_in[3];
  const float* bk = (const float*)d_in[4];
  const float* Wv = (const float*)d_in[5];
  const float* bv = (const float*)d_in[6];
  float* out = (float*)d_out;

  // ws layout (70 MB bf16 + 16 KB fp32). G3 split-K=4 partials reuse dead
  // regions: Xb (dead after G1), Qb, Kb (dead after G2); z=3 goes to d_out.
  bf16_t* Xb = (bf16_t*)d_ws;            // [4096][1024]
  bf16_t* Wb = Xb + (size_t)S * D;       // [3072][1024]
  bf16_t* Qb = Wb + (size_t)3 * D * D;   // [4096][1024], pre-scaled by 1/32
  bf16_t* Kb = Qb + (size_t)S * D;       // [4096][1024]
  bf16_t* Vt = Kb + (size_t)S * D;       // [1024][4096]  V transposed
  bf16_t* Sc = Vt + (size_t)D * S;       // [4096][4096]  exp(scores)
  float* rowsum = (float*)(Sc + (size_t)S * S);  // [4096]

  cvt_all<<<7184, 256, 0, stream>>>(X, Wq, Wk, Wv, Xb, Wb, rowsum);

  // G1: QKV = Xb @ Wb^T + bias  (M=4096, N=3072, K=1024), 384 blocks
  gemm3<0><<<384, 512, 0, stream>>>(
      Xb, Wb, D, D, Qb, Kb, Vt, bq, bk, bv, nullptr, nullptr);
  // G2: Sc = exp(Qb @ Kb^T), rowsum partials  (M=N=4096, K=1024), 512 blocks
  gemm3<1><<<512, 512, 0, stream>>>(
      Qb, Kb, D, D, Sc, nullptr, nullptr, nullptr, nullptr, nullptr, nullptr,
      rowsum);
  // G3: O-partials = (Sc @ Vt^T)/rowsum, K split 4x1024, 512 blocks
  gemm3<2><<<512, 512, 0, stream>>>(
      Sc, Vt, S, S / 4, Xb, Qb, Kb, nullptr, nullptr, nullptr, out, rowsum);
  // out += p0 + p1 + p2
  reduce_out<<<S * D / 8 / 256, 256, 0, stream>>>(Xb, Qb, Kb, out);
}

// Round 10
// 216.217 us; speedup vs baseline: 1.0284x; 1.0284x over previous
//
#include <hip/hip_runtime.h>
#include <hip/hip_bf16.h>
#include <stdint.h>

// ScaledDotProductAttention S=4096 D=1024 fp32.
// R18: faithful m201 8-phase counted-vmcnt schedule, re-derived from template
// geometry (2 G-loads/half-tile, 4-or-8 ds_reads/phase, 16 MFMA/phase, vmcnt(6)
// at ph4/ph8 only). Key insight vs failed R12/R13: LDS halves are K-HALVES
// (256 rows x 32 k), each retired in ONE phase -> stage exactly 1 half/phase
// into last phase's retired slot; 2 K-tiles per iteration; 3 halves always in
// flight (queue never drains -> kills the drain duty-cycle that capped
// R14-R17 at ~45-53us). Retire/stage ladder (buf0=tiles 2i, buf1=2i+1):
//   ph1 rd A0ks0(im0-3)+B0ks0 | stage T1.A1   ph5 rd A1ks0(im0-3)+B1ks0 | T2.A1
//   ph2 rd A0ks0(im4-7)       | stage T2.B0   ph6 rd A1ks0(im4-7)       | T3.B0
//   ph3 rd A0ks1(im0-3)+B0ks1 | stage T2.A0   ph7 rd A1ks1(im0-3)+B1ks1 | T3.A0
//   ph4 rd A0ks1(im4-7)       | stage T2.B1   ph8 rd A1ks1(im4-7)       | T3.B1
//        + vmcnt(6)                                + vmcnt(6)
// Landed-proofs: ph4's vmcnt(6) leaves {ph2,3,4}=6 outstanding => T1 (prev
// ph6,7,8 + this ph1) fully landed before ph5 reads it. ph8's vmcnt(6) leaves
// {ph6,7,8} => T2 (ph2,3,4,5) fully landed before next ph1. Slot-reuse: each
// staged slot was retired (last ds_read drained at that phase's lgkmcnt(0),
// which precedes its end-barrier) one phase earlier. Tail: vmcnt(0) when the
// corresponding stage predicate is false. Epilogues/grids verbatim from R15
// (passed): j-inner stores (R13 WC fix), V^T 2-pass 264-stride LDS transpose.

typedef __bf16 bf16_t;
typedef __bf16 bf16x4 __attribute__((ext_vector_type(4)));
typedef __bf16 bf16x8 __attribute__((ext_vector_type(8)));
typedef float f32x4 __attribute__((ext_vector_type(4)));

#define AS1 __attribute__((address_space(1)))
#define AS3 __attribute__((address_space(3)))

__device__ __forceinline__ void async_ld16(const void* g, void* l) {
  // global -> LDS DMA, 16B/lane; LDS dest is wave-uniform base + lane*16 by HW rule.
  __builtin_amdgcn_global_load_lds((AS1 void*)g, (AS3 void*)l, 16, 0, 0);
}

#define BAR() __builtin_amdgcn_s_barrier()
#define LGKM0() asm volatile("s_waitcnt lgkmcnt(0)" ::: "memory")
#define VM6() asm volatile("s_waitcnt vmcnt(6)" ::: "memory")
#define VM0() asm volatile("s_waitcnt vmcnt(0)" ::: "memory")

// 256x256 tile, BK=64, 8 waves (2M x 4N), per-wave 128x64 = acc[8][4].
// LDS (dynamic 128KB, elems): buf0 A@0 B@16384 | buf1 A@32768 B@49152.
// Each A/B buffer = 2 K-halves x 8192 elems (256 rows x 32 k).
// MODE 0: QKV epilogue (bias; Q scaled 1/32; V transposed via LDS).
// MODE 1: S epilogue: store exp(acc) bf16 ldc=4096, atomicAdd fp32 row sums.
// MODE 2: O epilogue: zz<3 -> bf16 partial; zz==3 -> fp32 to fout (1/rowsum).
template <int MODE>
__global__ __launch_bounds__(512, 2) void gemm8p(
    const bf16_t* __restrict__ A, const bf16_t* __restrict__ B, const int ld,
    const int Klen, bf16_t* __restrict__ o0, bf16_t* __restrict__ o1,
    bf16_t* __restrict__ o2, const float* __restrict__ b0,
    const float* __restrict__ b1, const float* __restrict__ b2,
    float* __restrict__ fout, float* __restrict__ rowsum) {
  extern __shared__ bf16_t smem[];  // 131072 B

  const int t = threadIdx.x;
  const int lane = t & 63;
  const int wave = t >> 6;
  const int wm = wave >> 2;   // 0..1  (M half: 128 rows)
  const int wn = wave & 3;    // 0..3  (N quarter: 64 cols)
  const int q = lane >> 4;
  const int l16 = lane & 15;

  // Grid decode: XCD-aware (bid&7 = XCD), bijective per mode (R15-proven).
  int m0, n0, k0 = 0, zz = 0;
  const int bid = blockIdx.x;
  if constexpr (MODE == 0) {
    const int x = bid & 7, sl = bid >> 3;  // 192 blocks = 16m x 12n
    m0 = ((x >> 1) * 4 + (sl & 3)) * 256;
    n0 = ((x & 1) * 6 + (sl >> 2)) * 256;
  } else if constexpr (MODE == 1) {
    const int x = bid & 7, sl = bid >> 3;  // 256 blocks = 16m x 16n
    m0 = ((x >> 2) * 8 + (sl >> 2)) * 256;
    n0 = ((x & 3) * 4 + (sl & 3)) * 256;
  } else {
    const int x = bid & 7, sl = bid >> 3;  // 256 blocks: 4z x 8m x 4n
    zz = x >> 1;
    m0 = ((x & 1) * 8 + (sl >> 2)) * 256;
    n0 = (sl & 3) * 256;
    k0 = zz * Klen;
  }

  // Staging: one K-half (256 rows x 32 k) = 2 loads x 512 thr x 16B.
  // Swizzle (R5 algebra, CH=4): LDS slot t&3 at row t>>2 holds GLOBAL chunk
  // (t&3)^(row&3); read side inverts with l16&3.
  const int srow2 = t >> 2;                       // 0..127
  const int c4s = (((t & 3) ^ (srow2 & 3)) * 8);
  const bf16_t* Ab = A + (size_t)(m0 + srow2) * ld + k0 + c4s;
  const bf16_t* Bb = B + (size_t)(n0 + srow2) * ld + k0 + c4s;
  const int tl8 = t * 8;
  const size_t r128 = (size_t)128 * ld;

  bf16_t* A0 = smem;
  bf16_t* B0 = smem + 16384;
  bf16_t* A1 = smem + 32768;
  bf16_t* B1s = smem + 49152;

  // Read bases: frag (im,ks) at row wm*128+im*16+l16, slot q^(l16&3).
  const int xsl = (q ^ (l16 & 3)) * 8;
  const int aBase = (wm * 128 + l16) * 32 + xsl;
  const int bBase = (wn * 64 + l16) * 32 + xsl;

  f32x4 acc[8][4];
  const f32x4 zero4 = {0.f, 0.f, 0.f, 0.f};
#pragma unroll
  for (int i = 0; i < 8; ++i)
#pragma unroll
    for (int j = 0; j < 4; ++j) acc[i][j] = zero4;

  const int NT = Klen >> 6;  // 16

  auto STG = [&](const bf16_t* gb, bf16_t* lbuf, int tile, int ksh) {
    const int ko = tile * 64 + ksh * 32;
    async_ld16(gb + ko, lbuf + ksh * 8192 + tl8);
    async_ld16(gb + r128 + ko, lbuf + ksh * 8192 + 4096 + tl8);
  };

  // Prologue: T0 {B0,A0,B1,A1} then T1 {B0,A0,B1}; vmcnt(6) drains exactly T0.
  STG(Bb, B0, 0, 0); STG(Ab, A0, 0, 0); STG(Bb, B0, 0, 1); STG(Ab, A0, 0, 1);
  STG(Bb, B1s, 1, 0); STG(Ab, A1, 1, 0); STG(Bb, B1s, 1, 1);
  VM6();
  BAR();

  for (int it = 0; it < NT / 2; ++it) {
    const int T1 = 2 * it + 1, T2 = 2 * it + 2, T3 = 2 * it + 3;
    const bool s2 = T2 < NT, s3 = T3 < NT;
    bf16x8 fa[4], fb0[4], fb1[4];

#define RDA(bufA, ks, img)                                              \
  _Pragma("unroll") for (int im = 0; im < 4; ++im) fa[im] =             \
      *(const bf16x8*)(bufA + (ks) * 8192 + aBase + ((img) * 4 + im) * 512);
#define RDB(bufB, ks, fb)                                               \
  _Pragma("unroll") for (int j = 0; j < 4; ++j) fb[j] =                 \
      *(const bf16x8*)(bufB + (ks) * 8192 + bBase + j * 512);
#define MM(fb, img)                                                     \
  __builtin_amdgcn_s_setprio(1);                                        \
  _Pragma("unroll") for (int im = 0; im < 4; ++im)                      \
      _Pragma("unroll") for (int j = 0; j < 4; ++j)                     \
          acc[(img) * 4 + im][j] = __builtin_amdgcn_mfma_f32_16x16x32_bf16( \
              fa[im], fb[j], acc[(img) * 4 + im][j], 0, 0, 0);          \
  __builtin_amdgcn_s_setprio(0);

    // ph1
    RDA(A0, 0, 0); RDB(B0, 0, fb0);
    STG(Ab, A1, T1, 1);
    BAR(); LGKM0(); MM(fb0, 0); BAR();
    // ph2
    RDA(A0, 0, 1);
    if (s2) STG(Bb, B0, T2, 0);
    BAR(); LGKM0(); MM(fb0, 1); BAR();
    // ph3
    RDA(A0, 1, 0); RDB(B0, 1, fb1);
    if (s2) STG(Ab, A0, T2, 0);
    BAR(); LGKM0(); MM(fb1, 0); BAR();
    // ph4
    RDA(A0, 1, 1);
    if (s2) STG(Bb, B0, T2, 1);
    BAR(); LGKM0(); MM(fb1, 1);
    if (s2) { VM6(); } else { VM0(); }
    BAR();
    // ph5
    RDA(A1, 0, 0); RDB(B1s, 0, fb0);
    if (s2) STG(Ab, A0, T2, 1);
    BAR(); LGKM0(); MM(fb0, 0); BAR();
    // ph6
    RDA(A1, 0, 1);
    if (s3) STG(Bb, B1s, T3, 0);
    BAR(); LGKM0(); MM(fb0, 1); BAR();
    // ph7
    RDA(A1, 1, 0); RDB(B1s, 1, fb1);
    if (s3) STG(Ab, A1, T3, 0);
    BAR(); LGKM0(); MM(fb1, 0); BAR();
    // ph8
    RDA(A1, 1, 1);
    if (s3) STG(Bb, B1s, T3, 1);
    BAR(); LGKM0(); MM(fb1, 1);
    if (s3) { VM6(); } else { VM0(); }
    BAR();
#undef RDA
#undef RDB
#undef MM
  }

  // C/D layout: col = lane&15, row = quad*4 + reg (m89/m91-verified).
  const int mW = m0 + wm * 128 + q * 4;  // + im*16 + r

  if constexpr (MODE == 0) {
    const int sel = n0 >> 10;  // 0=Q 1=K 2=V  (256-tiles never straddle)
    const int nl0 = (n0 & 1023) + wn * 64 + l16;
    if (sel < 2) {
      const float* bias = (sel == 0) ? b0 : b1;
      const float sc = (sel == 0) ? 0.03125f : 1.0f;  // 1/sqrt(1024) in Q
      bf16_t* dst = (sel == 0) ? o0 : o1;
      float bb[4];
#pragma unroll
      for (int j = 0; j < 4; ++j) bb[j] = bias[nl0 + j * 16];
      // j INNERMOST: 4 consecutive stores complete each 128B run (R13 fix).
#pragma unroll
      for (int im = 0; im < 8; ++im) {
        const int mr = mW + im * 16;
#pragma unroll
        for (int r = 0; r < 4; ++r)
#pragma unroll
          for (int j = 0; j < 4; ++j)
            dst[(size_t)(mr + r) * 1024 + nl0 + j * 16] =
                (bf16_t)((acc[im][j][r] + bb[j]) * sc);
      }
    } else {
      // V^T via LDS transpose (R15-verbatim): two passes of 128 d-rows x
      // 256 m; stride 264 elems; 16B/lane drain, 512B contiguous per row.
      bf16_t* vs = smem;  // 128*264*2 = 67584 B (K-loop buffers dead)
      const int dg0 = n0 & 1023;
#pragma unroll
      for (int h = 0; h < 2; ++h) {
        if ((wn >> 1) == h) {
#pragma unroll
          for (int j = 0; j < 4; ++j) {
            const int dl = (wn & 1) * 64 + j * 16 + l16;  // 0..127
            const float bb = b2[dg0 + h * 128 + dl];
#pragma unroll
            for (int im = 0; im < 8; ++im) {
              bf16x4 v;
#pragma unroll
              for (int r = 0; r < 4; ++r) v[r] = (bf16_t)(acc[im][j][r] + bb);
              *(bf16x4*)(vs + dl * 264 + wm * 128 + im * 16 + q * 4) = v;
            }
          }
        }
        __syncthreads();
#pragma unroll
        for (int rr = 0; rr < 8; ++rr) {
          const int task = rr * 512 + t;
          const int row = task >> 5, ck = task & 31;
          *(bf16x8*)(o2 + (size_t)(dg0 + h * 128 + row) * 4096 + m0 + ck * 8) =
              *(const bf16x8*)(vs + row * 264 + ck * 8);
        }
        __syncthreads();
      }
    }
  } else if constexpr (MODE == 1) {
    float ps[8][4];
#pragma unroll
    for (int im = 0; im < 8; ++im)
#pragma unroll
      for (int r = 0; r < 4; ++r) ps[im][r] = 0.f;
    const int nb = n0 + wn * 64 + l16;
    // j INNERMOST: complete 128B runs back-to-back (R13 write-combine fix).
#pragma unroll
    for (int im = 0; im < 8; ++im) {
      const int mr = mW + im * 16;
#pragma unroll
      for (int r = 0; r < 4; ++r)
#pragma unroll
        for (int j = 0; j < 4; ++j) {
          const float e = __expf(acc[im][j][r]);
          ps[im][r] += e;
          o0[(size_t)(mr + r) * 4096 + nb + j * 16] = (bf16_t)e;
        }
    }
#pragma unroll
    for (int im = 0; im < 8; ++im)
#pragma unroll
      for (int r = 0; r < 4; ++r) {
        float v = ps[im][r];
        v += __shfl_xor(v, 1);
        v += __shfl_xor(v, 2);
        v += __shfl_xor(v, 4);
        v += __shfl_xor(v, 8);
        ps[im][r] = v;
      }
    if (l16 == 0) {
#pragma unroll
      for (int im = 0; im < 8; ++im)
#pragma unroll
        for (int r = 0; r < 4; ++r)
          atomicAdd(rowsum + mW + im * 16 + r, ps[im][r]);
    }
  } else {
    float inv[8][4];
#pragma unroll
    for (int im = 0; im < 8; ++im)
#pragma unroll
      for (int r = 0; r < 4; ++r)
        inv[im][r] = 1.0f / rowsum[mW + im * 16 + r];
    const int nb = n0 + wn * 64 + l16;
    if (zz < 3) {  // bf16 partial (normalized); partials over splits sum to O
      bf16_t* pp = (zz == 0) ? o0 : ((zz == 1) ? o1 : o2);
#pragma unroll
      for (int im = 0; im < 8; ++im) {
        const int mr = mW + im * 16;
#pragma unroll
        for (int r = 0; r < 4; ++r) {
          const float iv = inv[im][r];
#pragma unroll
          for (int j = 0; j < 4; ++j)
            pp[(size_t)(mr + r) * 1024 + nb + j * 16] =
                (bf16_t)(acc[im][j][r] * iv);
        }
      }
    } else {  // zz==3: fp32 partial straight into d_out; reduce adds the rest
#pragma unroll
      for (int im = 0; im < 8; ++im) {
        const int mr = mW + im * 16;
#pragma unroll
        for (int r = 0; r < 4; ++r) {
          const float iv = inv[im][r];
#pragma unroll
          for (int j = 0; j < 4; ++j)
            fout[(size_t)(mr + r) * 1024 + nb + j * 16] = acc[im][j][r] * iv;
        }
      }
    }
  }
}

// Converts X|Wq|Wk|Wv to bf16; last 16 blocks zero rowsum (4096 f32).
__global__ __launch_bounds__(256) void cvt_all(
    const float* __restrict__ X, const float* __restrict__ Wq,
    const float* __restrict__ Wk, const float* __restrict__ Wv,
    bf16_t* __restrict__ Xb, bf16_t* __restrict__ Wb,
    float* __restrict__ rowsum) {
  int i = blockIdx.x * 256 + threadIdx.x;
  if (i >= 1835008) {
    rowsum[i - 1835008] = 0.f;
    return;
  }
  const float* src;
  bf16_t* dst;
  int off;
  if (i < 1048576) {
    src = X; dst = Xb; off = i;
  } else {
    const int w = i - 1048576;
    const int sel = w >> 18;
    off = w & 0x3FFFF;
    src = (sel == 0) ? Wq : ((sel == 1) ? Wk : Wv);
    dst = Wb + (size_t)sel * (1024 * 1024);
  }
  const float4 v = ((const float4*)src)[off];
  bf16x4 o;
  o[0] = (bf16_t)v.x; o[1] = (bf16_t)v.y; o[2] = (bf16_t)v.z; o[3] = (bf16_t)v.w;
  ((bf16x4*)dst)[off] = o;
}

// out[i] += f32(p0[i]) + f32(p1[i]) + f32(p2[i]);  8 elems/thread.
__global__ __launch_bounds__(256) void reduce_out(
    const bf16_t* __restrict__ p0, const bf16_t* __restrict__ p1,
    const bf16_t* __restrict__ p2, float* __restrict__ out) {
  const int i = blockIdx.x * 256 + threadIdx.x;
  const bf16x8 a = ((const bf16x8*)p0)[i];
  const bf16x8 b = ((const bf16x8*)p1)[i];
  const bf16x8 c = ((const bf16x8*)p2)[i];
  float4 lo = ((const float4*)out)[2 * i];
  float4 hi = ((const float4*)out)[2 * i + 1];
  lo.x += (float)a[0] + (float)b[0] + (float)c[0];
  lo.y += (float)a[1] + (float)b[1] + (float)c[1];
  lo.z += (float)a[2] + (float)b[2] + (float)c[2];
  lo.w += (float)a[3] + (float)b[3] + (float)c[3];
  hi.x += (float)a[4] + (float)b[4] + (float)c[4];
  hi.y += (float)a[5] + (float)b[5] + (float)c[5];
  hi.z += (float)a[6] + (float)b[6] + (float)c[6];
  hi.w += (float)a[7] + (float)b[7] + (float)c[7];
  ((float4*)out)[2 * i] = lo;
  ((float4*)out)[2 * i + 1] = hi;
}

extern "C" void kernel_launch(void* const* d_in, const int* in_sizes, int n_in,
                              void* d_out, int out_size, void* d_ws,
                              size_t ws_size, hipStream_t stream) {
  const int S = 4096, D = 1024;
  const float* X  = (const float*)d_in[0];
  const float* Wq = (const float*)d_in[1];
  const float* bq = (const float*)d_in[2];
  const float* Wk = (const float*)d_in[3];
  const float* bk = (const float*)d_in[4];
  const float* Wv = (const float*)d_in[5];
  const float* bv = (const float*)d_in[6];
  float* out = (float*)d_out;

  // ws layout (70 MB bf16 + 16 KB fp32). G3 split-K=4 partials reuse dead
  // regions: Xb (dead after G1), Qb, Kb (dead after G2); z=3 goes to d_out.
  bf16_t* Xb = (bf16_t*)d_ws;            // [4096][1024]
  bf16_t* Wb = Xb + (size_t)S * D;       // [3072][1024]
  bf16_t* Qb = Wb + (size_t)3 * D * D;   // [4096][1024], pre-scaled by 1/32
  bf16_t* Kb = Qb + (size_t)S * D;       // [4096][1024]
  bf16_t* Vt = Kb + (size_t)S * D;       // [1024][4096]  V transposed
  bf16_t* Sc = Vt + (size_t)D * S;       // [4096][4096]  exp(scores)
  float* rowsum = (float*)(Sc + (size_t)S * S);  // [4096]

  // 128 KiB dynamic LDS opt-in (idempotent; capture-safe — ran fine in R15).
  static int attr_set = 0;
  if (!attr_set) {
    attr_set = 1;
    (void)hipFuncSetAttribute(reinterpret_cast<const void*>(gemm8p<0>),
                              hipFuncAttributeMaxDynamicSharedMemorySize,
                              131072);
    (void)hipFuncSetAttribute(reinterpret_cast<const void*>(gemm8p<1>),
                              hipFuncAttributeMaxDynamicSharedMemorySize,
                              131072);
    (void)hipFuncSetAttribute(reinterpret_cast<const void*>(gemm8p<2>),
                              hipFuncAttributeMaxDynamicSharedMemorySize,
                              131072);
  }

  cvt_all<<<7184, 256, 0, stream>>>(X, Wq, Wk, Wv, Xb, Wb, rowsum);

  // G1: QKV = Xb @ Wb^T + bias  (M=4096, N=3072, K=1024), 192 blocks
  gemm8p<0><<<192, 512, 131072, stream>>>(
      Xb, Wb, D, D, Qb, Kb, Vt, bq, bk, bv, nullptr, nullptr);
  // G2: Sc = exp(Qb @ Kb^T), rowsum partials  (M=N=4096, K=1024), 256 blocks
  gemm8p<1><<<256, 512, 131072, stream>>>(
      Qb, Kb, D, D, Sc, nullptr, nullptr, nullptr, nullptr, nullptr, nullptr,
      rowsum);
  // G3: O-partials = (Sc @ Vt^T)/rowsum, K split 4x1024, 256 blocks
  gemm8p<2><<<256, 512, 131072, stream>>>(
      Sc, Vt, S, S / 4, Xb, Qb, Kb, nullptr, nullptr, nullptr, out, rowsum);
  // out += p0 + p1 + p2
  reduce_out<<<S * D / 8 / 256, 256, 0, stream>>>(Xb, Qb, Kb, out);
}